// Round 7
// baseline (726.942 us; speedup 1.0000x reference)
//
#include <hip/hip_runtime.h>
#include <hip/hip_bf16.h>
#include <math.h>

#define NB 32
#define NQ 2048
#define NK 512
#define NE 16
#define NH 32
#define NL 20
#define NHID 50
#define NO 41

// ws layout (floats):
// att  : [65536][64]   @ 0        (4,194,304)  normalized P@val (pre-Wv)
// val  : [32][512][64] @ 4194304  (1,048,576)
// ktab : [512][16]     @ 5242880  (8,192)
// w1p  : [50][64]      @ 5251072  (3,200)      W1 @ Wv
// b1p  : [50]          @ 5254272  (50)         b1 + W1 @ bv

__device__ __forceinline__ float fsigmoid(float x) {
  return __builtin_amdgcn_rcpf(1.0f + __expf(-x));
}
__device__ __forceinline__ float ftanh(float x) {
  return 1.0f - 2.0f * __builtin_amdgcn_rcpf(__expf(2.0f * x) + 1.0f);
}

// blocks 0-1: k-table. block 2: fold Wv into W1 (softmax rows sum to 1 =>
// P@(val@Wv^T+bv) == (P@val)@Wv^T+bv; then W1@(ar@Wv^T+bv) = (W1@Wv)@ar + (b1+W1@bv)).
__global__ __launch_bounds__(256) void prep_kernel(
    const float* __restrict__ refq, const float* __restrict__ Wk,
    const float* __restrict__ bk,
    const float* __restrict__ Wv, const float* __restrict__ bv,
    const float* __restrict__ W1, const float* __restrict__ b1,
    float* __restrict__ ktab, float* __restrict__ w1p,
    float* __restrict__ b1p) {
  const int tid = threadIdx.x;
  if (blockIdx.x < 2) {
    const int r = blockIdx.x * 256 + tid;
    const float divs[8] = {1.0f, 0.74989421f, 0.56234133f, 0.42169650f,
                           0.31622777f, 0.23713737f, 0.17782794f, 0.13335214f};
    float pos = refq[r];
    float emb[NE];
#pragma unroll
    for (int m = 0; m < 8; ++m) {
      float a = 48.0f * pos * divs[m];
      emb[2 * m] = sinf(a);
      emb[2 * m + 1] = cosf(a);
    }
#pragma unroll
    for (int e = 0; e < NE; ++e) {
      float acc = bk[e];
#pragma unroll
      for (int i = 0; i < NE; ++i) acc += emb[i] * Wk[e * NE + i];
      ktab[r * NE + e] = acc;
    }
  } else {
    for (int e = tid; e < NHID * 64; e += 256) {
      const int o = e >> 6, i = e & 63;
      float acc = 0.f;
#pragma unroll 4
      for (int d = 0; d < 64; ++d) acc += W1[o * 64 + d] * Wv[d * 64 + i];
      w1p[e] = acc;
    }
    if (tid < NHID) {
      float acc = b1[tid];
#pragma unroll 4
      for (int d = 0; d < 64; ++d) acc += W1[tid * 64 + d] * bv[d];
      b1p[tid] = acc;
    }
  }
}

// One wave per chain. h lives in registers; per-step gather via __shfl.
__global__ __launch_bounds__(64) void gru_kernel(
    const float* __restrict__ z,
    const float* __restrict__ Wih_f, const float* __restrict__ bih_f,
    const float* __restrict__ Whh_f, const float* __restrict__ bhh_f,
    const float* __restrict__ Wih_b, const float* __restrict__ bih_b,
    const float* __restrict__ Whh_b, const float* __restrict__ bhh_b,
    float* __restrict__ val) {
  __shared__ __align__(16) float zs[NK * NL];  // 40 KB
  const int c = blockIdx.x;
  const int dir = c >> 5, b = c & 31;
  const int l = threadIdx.x;
  const int j = l & 31, half = l >> 5;
  const int hbase = half * 16;
  const float* __restrict__ zb = z + (size_t)b * NK * NL;
  for (int i = l; i < NK * NL; i += 64) zs[i] = zb[i];

  const float* __restrict__ Wih = dir ? Wih_b : Wih_f;
  const float* __restrict__ bih = dir ? bih_b : bih_f;
  const float* __restrict__ Whh = dir ? Whh_b : Whh_f;
  const float* __restrict__ bhh = dir ? bhh_b : bhh_f;

  float ur[10], uz[10], un[10];
#pragma unroll
  for (int i = 0; i < 10; ++i) {
    ur[i] = Wih[j * NL + half * 10 + i];
    uz[i] = Wih[(j + 32) * NL + half * 10 + i];
    un[i] = Wih[(j + 64) * NL + half * 10 + i];
  }
  float wr[16], wz[16], wn[16];
#pragma unroll
  for (int i = 0; i < 16; ++i) {
    wr[i] = Whh[j * 32 + hbase + i];
    wz[i] = Whh[(j + 32) * 32 + hbase + i];
    wn[i] = Whh[(j + 64) * 32 + hbase + i];
  }
  const float Br = bih[j] + bhh[j];
  const float Bz = bih[j + 32] + bhh[j + 32];
  const float bin_ = bih[j + 64], bhn = bhh[j + 64];
  float h = 0.f;
  __syncthreads();

  float pir, piz, pin;
  auto inpart = [&](int s, float& xr, float& xz, float& xn) {
    const int tt = dir ? (NK - 1 - s) : s;
    const float* zr = &zs[tt * NL + half * 10];
    float ar = 0.f, az = 0.f, an = 0.f;
#pragma unroll
    for (int i = 0; i < 10; ++i) {
      const float zi = zr[i];
      ar += ur[i] * zi;
      az += uz[i] * zi;
      an += un[i] * zi;
    }
    xr = ar; xz = az; xn = an;
  };
  inpart(0, pir, piz, pin);

  for (int s = 0; s < NK; ++s) {
    float hv[16];
#pragma unroll
    for (int t = 0; t < 16; ++t) hv[t] = __shfl(h, hbase + t);
    float pr0 = 0.f, pr1 = 0.f, pz0 = 0.f, pz1 = 0.f, pn0 = 0.f, pn1 = 0.f;
#pragma unroll
    for (int t = 0; t < 8; ++t) {
      pr0 += wr[t] * hv[t];
      pz0 += wz[t] * hv[t];
      pn0 += wn[t] * hv[t];
      pr1 += wr[8 + t] * hv[8 + t];
      pz1 += wz[8 + t] * hv[8 + t];
      pn1 += wn[8 + t] * hv[8 + t];
    }
    const float cr = pir + pr0 + pr1;
    const float cz = piz + pz0 + pz1;
    const float phn = pn0 + pn1;
    const float cni = pin;
    const float sr = cr + __shfl_xor(cr, 32);
    const float sz = cz + __shfl_xor(cz, 32);
    const float sni = cni + __shfl_xor(cni, 32);
    const float snh = phn + __shfl_xor(phn, 32);
    if (s + 1 < NK) inpart(s + 1, pir, piz, pin);
    const float rg = fsigmoid(sr + Br);
    const float ug = fsigmoid(sz + Bz);
    const float ng = ftanh(sni + bin_ + rg * (snh + bhn));
    h = ng + ug * (h - ng);
    if (half == 0) {
      const int tt = dir ? (NK - 1 - s) : s;
      val[((size_t)b * NK + tt) * 64 + dir * 32 + j] = h;
    }
  }
}

// Non-redundant k-interleaved split: lane dq of each 4-lane row group handles
// k = 4i+dq (scores+exp: 1/4 of the work), shares p via 4 bpermutes, and
// accumulates only its d-quarter (acc[16] -> ~64 VGPR, no combine epilogue).
__global__ __launch_bounds__(256) void attn_core_kernel(
    const float* __restrict__ tsteps, const float* __restrict__ ktab,
    const float* __restrict__ val,
    const float* __restrict__ Wq, const float* __restrict__ bq,
    float* __restrict__ att) {
  __shared__ __align__(16) float kt[NK * NE];  // 32 KB
  __shared__ float wqs[NE * NE];
  __shared__ float bqs[NE];
  const int tid = threadIdx.x;
  for (int i = tid; i < NK * NE; i += 256) kt[i] = ktab[i];
  for (int i = tid; i < NE * NE; i += 256) wqs[i] = Wq[i];
  if (tid < NE) bqs[tid] = bq[tid];
  __syncthreads();

  const int g = blockIdx.x * 256 + tid;
  const int row = g >> 2;      // b*2048 + qi
  const int dq = g & 3;        // d-quarter / k-phase
  const int b = row >> 11;
  const float pos = tsteps[row];
  const float divs[8] = {1.0f, 0.74989421f, 0.56234133f, 0.42169650f,
                         0.31622777f, 0.23713737f, 0.17782794f, 0.13335214f};
  float emb[NE];
#pragma unroll
  for (int m = 0; m < 8; ++m) {
    float a = 48.0f * pos * divs[m];
    emb[2 * m] = sinf(a);
    emb[2 * m + 1] = cosf(a);
  }
  float q[NE];
#pragma unroll
  for (int e = 0; e < NE; ++e) {
    float acc = bqs[e];
#pragma unroll
    for (int i = 0; i < NE; ++i) acc += emb[i] * wqs[e * NE + i];
    q[e] = acc * 0.25f;  // fold 1/sqrt(E) into q
  }
  // bpermute lane addresses for the 4 group members (byte addr = lane*4)
  const int gb = (tid & ~3);
  const int a0 = (gb + 0) << 2, a1 = (gb + 1) << 2;
  const int a2 = (gb + 2) << 2, a3 = (gb + 3) << 2;

  const float* __restrict__ vb = val + (size_t)b * NK * 64 + dq * 16;
  float acc[16];
#pragma unroll
  for (int d = 0; d < 16; ++d) acc[d] = 0.f;
  float lsum = 0.f;
  // scores O(1) (0.1-scale weights): exp without max-sub safe in fp32
#pragma unroll 2
  for (int i = 0; i < NK / 4; ++i) {
    const int k = (i << 2) | dq;  // this lane's k
    const float4* kr = (const float4*)&kt[k * NE];
    float s = 0.f;
#pragma unroll
    for (int e4 = 0; e4 < 4; ++e4) {
      float4 kk = kr[e4];
      s += q[e4 * 4 + 0] * kk.x + q[e4 * 4 + 1] * kk.y +
           q[e4 * 4 + 2] * kk.z + q[e4 * 4 + 3] * kk.w;
    }
    const float p = __expf(s);
    // share the 4 p's across the row group (j-indexed, lane-order exact)
    const float p0 = __builtin_bit_cast(
        float, __builtin_amdgcn_ds_bpermute(a0, __builtin_bit_cast(int, p)));
    const float p1 = __builtin_bit_cast(
        float, __builtin_amdgcn_ds_bpermute(a1, __builtin_bit_cast(int, p)));
    const float p2 = __builtin_bit_cast(
        float, __builtin_amdgcn_ds_bpermute(a2, __builtin_bit_cast(int, p)));
    const float p3 = __builtin_bit_cast(
        float, __builtin_amdgcn_ds_bpermute(a3, __builtin_bit_cast(int, p)));
    lsum += (p0 + p1) + (p2 + p3);
    const float* vrow = vb + (size_t)(i << 2) * 64;
    const float4* v0 = (const float4*)(vrow);
    const float4* v1 = (const float4*)(vrow + 64);
    const float4* v2 = (const float4*)(vrow + 128);
    const float4* v3 = (const float4*)(vrow + 192);
#pragma unroll
    for (int d4 = 0; d4 < 4; ++d4) {
      const float4 w0 = v0[d4], w1 = v1[d4], w2 = v2[d4], w3 = v3[d4];
      acc[d4 * 4 + 0] += p0 * w0.x + p1 * w1.x + p2 * w2.x + p3 * w3.x;
      acc[d4 * 4 + 1] += p0 * w0.y + p1 * w1.y + p2 * w2.y + p3 * w3.y;
      acc[d4 * 4 + 2] += p0 * w0.z + p1 * w1.z + p2 * w2.z + p3 * w3.z;
      acc[d4 * 4 + 3] += p0 * w0.w + p1 * w1.w + p2 * w2.w + p3 * w3.w;
    }
  }
  const float inv = 1.0f / lsum;
  float4* ao = (float4*)(att + (size_t)row * 64 + dq * 16);
#pragma unroll
  for (int d4 = 0; d4 < 4; ++d4) {
    float4 o;
    o.x = acc[d4 * 4 + 0] * inv;
    o.y = acc[d4 * 4 + 1] * inv;
    o.z = acc[d4 * 4 + 2] * inv;
    o.w = acc[d4 * 4 + 3] * inv;
    ao[d4] = o;
  }
}

// Per-row MLP on folded weights: out = W2 @ relu(W1' @ ar + b1') + b2.
__global__ __launch_bounds__(256) void mlp_kernel(
    const float* __restrict__ att,
    const float* __restrict__ w1p, const float* __restrict__ b1p,
    const float* __restrict__ W2, const float* __restrict__ b2,
    float* __restrict__ out) {
  __shared__ __align__(16) float w1s[NHID * 64];   // 12.8 KB
  __shared__ __align__(16) float w2s[NO * NHID];   // 8.2 KB
  __shared__ float b1s[NHID], b2s[NO];
  const int tid = threadIdx.x;
  for (int i = tid; i < NHID * 64; i += 256) w1s[i] = w1p[i];
  for (int i = tid; i < NO * NHID; i += 256) w2s[i] = W2[i];
  if (tid < NHID) b1s[tid] = b1p[tid];
  if (tid < NO) b2s[tid] = b2[tid];
  __syncthreads();

  const int row = blockIdx.x * 256 + tid;
  float ar[64];
  const float4* a4 = (const float4*)(att + (size_t)row * 64);
#pragma unroll
  for (int d4 = 0; d4 < 16; ++d4) {
    float4 v = a4[d4];
    ar[d4 * 4 + 0] = v.x;
    ar[d4 * 4 + 1] = v.y;
    ar[d4 * 4 + 2] = v.z;
    ar[d4 * 4 + 3] = v.w;
  }
  float outv[NO];
#pragma unroll
  for (int oo = 0; oo < NO; ++oo) outv[oo] = b2s[oo];
#pragma unroll 2
  for (int o = 0; o < NHID; ++o) {
    float acc = b1s[o];
    const float4* w4 = (const float4*)&w1s[o * 64];
#pragma unroll
    for (int i4 = 0; i4 < 16; ++i4) {
      float4 ww = w4[i4];
      acc += ar[i4 * 4 + 0] * ww.x + ar[i4 * 4 + 1] * ww.y +
             ar[i4 * 4 + 2] * ww.z + ar[i4 * 4 + 3] * ww.w;
    }
    const float hv = fmaxf(acc, 0.f);
#pragma unroll
    for (int oo = 0; oo < NO; ++oo) outv[oo] += hv * w2s[oo * NHID + o];
  }
  float* orow = out + (size_t)row * NO;
#pragma unroll
  for (int oo = 0; oo < NO; ++oo) orow[oo] = outv[oo];
}

extern "C" void kernel_launch(void* const* d_in, const int* in_sizes, int n_in,
                              void* d_out, int out_size, void* d_ws, size_t ws_size,
                              hipStream_t stream) {
  const float* z = (const float*)d_in[0];
  const float* ts = (const float*)d_in[1];
  const float* refq = (const float*)d_in[2];
  const float* Wih_f = (const float*)d_in[3];
  const float* Whh_f = (const float*)d_in[4];
  const float* bih_f = (const float*)d_in[5];
  const float* bhh_f = (const float*)d_in[6];
  const float* Wih_b = (const float*)d_in[7];
  const float* Whh_b = (const float*)d_in[8];
  const float* bih_b = (const float*)d_in[9];
  const float* bhh_b = (const float*)d_in[10];
  const float* Wq = (const float*)d_in[11];
  const float* bq = (const float*)d_in[12];
  const float* Wk = (const float*)d_in[13];
  const float* bk = (const float*)d_in[14];
  const float* Wv = (const float*)d_in[15];
  const float* bv = (const float*)d_in[16];
  const float* W1 = (const float*)d_in[17];
  const float* b1 = (const float*)d_in[18];
  const float* W2 = (const float*)d_in[19];
  const float* b2 = (const float*)d_in[20];

  float* ws = (float*)d_ws;
  float* att = ws;              // 4,194,304
  float* val = ws + 4194304;    // 1,048,576
  float* ktab = ws + 5242880;   // 8,192
  float* w1p = ws + 5251072;    // 3,200
  float* b1p = ws + 5254272;    // 50
  float* out = (float*)d_out;

  prep_kernel<<<3, 256, 0, stream>>>(refq, Wk, bk, Wv, bv, W1, b1,
                                     ktab, w1p, b1p);
  gru_kernel<<<64, 64, 0, stream>>>(z, Wih_f, bih_f, Whh_f, bhh_f,
                                    Wih_b, bih_b, Whh_b, bhh_b, val);
  attn_core_kernel<<<1024, 256, 0, stream>>>(ts, ktab, val, Wq, bq, att);
  mlp_kernel<<<256, 256, 0, stream>>>(att, w1p, b1p, W2, b2, out);
}

// Round 8
// 458.718 us; speedup vs baseline: 1.5847x; 1.5847x over previous
//
#include <hip/hip_runtime.h>
#include <hip/hip_bf16.h>
#include <math.h>

#define NB 32
#define NQ 2048
#define NK 512
#define NE 16
#define NH 32
#define NL 20
#define NHID 50
#define NO 41

// ws layout (floats):
// att  : [65536][64]   @ 0        (4,194,304)  normalized P@val (pre-Wv)
// val  : [32][512][64] @ 4194304  (1,048,576)
// ktab : [512][16]     @ 5242880  (8,192)
// w1p  : [50][64]      @ 5251072  (3,200)      W1 @ Wv
// b1p  : [50]          @ 5254272  (64)         b1 + W1 @ bv
// total ~21.0 MB (proven size)

__device__ __forceinline__ float fsigmoid(float x) {
  return __builtin_amdgcn_rcpf(1.0f + __expf(-x));
}
__device__ __forceinline__ float ftanh(float x) {
  return 1.0f - 2.0f * __builtin_amdgcn_rcpf(__expf(2.0f * x) + 1.0f);
}
__device__ __forceinline__ float bperm(int lane, float v) {
  return __builtin_bit_cast(
      float, __builtin_amdgcn_ds_bpermute(lane << 2, __builtin_bit_cast(int, v)));
}

// blocks 0-1: k-table. block 2: fold Wv into W1.
__global__ __launch_bounds__(256) void prep_kernel(
    const float* __restrict__ refq, const float* __restrict__ Wk,
    const float* __restrict__ bk,
    const float* __restrict__ Wv, const float* __restrict__ bv,
    const float* __restrict__ W1, const float* __restrict__ b1,
    float* __restrict__ ktab, float* __restrict__ w1p,
    float* __restrict__ b1p) {
  const int tid = threadIdx.x;
  if (blockIdx.x < 2) {
    const int r = blockIdx.x * 256 + tid;
    const float divs[8] = {1.0f, 0.74989421f, 0.56234133f, 0.42169650f,
                           0.31622777f, 0.23713737f, 0.17782794f, 0.13335214f};
    float pos = refq[r];
    float emb[NE];
#pragma unroll
    for (int m = 0; m < 8; ++m) {
      float a = 48.0f * pos * divs[m];
      emb[2 * m] = sinf(a);
      emb[2 * m + 1] = cosf(a);
    }
#pragma unroll
    for (int e = 0; e < NE; ++e) {
      float acc = bk[e];
#pragma unroll
      for (int i = 0; i < NE; ++i) acc += emb[i] * Wk[e * NE + i];
      ktab[r * NE + e] = acc;
    }
  } else {
    for (int e = tid; e < NHID * 64; e += 256) {
      const int o = e >> 6, i = e & 63;
      float acc = 0.f;
#pragma unroll 4
      for (int d = 0; d < 64; ++d) acc += W1[o * 64 + d] * Wv[d * 64 + i];
      w1p[e] = acc;
    }
    if (tid < NHID) {
      float acc = b1[tid];
#pragma unroll 4
      for (int d = 0; d < 64; ++d) acc += W1[tid * 64 + d] * bv[d];
      b1p[tid] = acc;
    }
  }
}

// One wave per chain. Per-step DS ops cut to ~12: z staged in padded LDS
// ([t][24]: two 12-float halves, pads zeroed) read as 3x ds_read_b128;
// h gathered via 1 ds_write + 4 broadcast ds_read_b128 (same-wave LDS is
// in-order, HW-proven in rounds 4-7).
__global__ __launch_bounds__(64) void gru_kernel(
    const float* __restrict__ z,
    const float* __restrict__ Wih_f, const float* __restrict__ bih_f,
    const float* __restrict__ Whh_f, const float* __restrict__ bhh_f,
    const float* __restrict__ Wih_b, const float* __restrict__ bih_b,
    const float* __restrict__ Whh_b, const float* __restrict__ bhh_b,
    float* __restrict__ val) {
  __shared__ __align__(16) float zs[NK * 24];  // 48 KB padded
  __shared__ __align__(16) float hbuf[NH];
  const int c = blockIdx.x;
  const int dir = c >> 5, b = c & 31;
  const int l = threadIdx.x;
  const int j = l & 31, half = l >> 5;
  const int hbase = half * 16;
  const float* __restrict__ zb = z + (size_t)b * NK * NL;
  // coalesced load with /20 via magic mul; scatter into padded layout
  for (int i = l; i < NK * NL; i += 64) {
    const unsigned t = __umulhi((unsigned)i, 0xCCCCCCCDu) >> 4;  // i/20
    const int r = i - (int)t * 20;
    zs[t * 24 + (r < 10 ? r : r + 2)] = zb[i];
  }
  // zero the pads (uninitialized LDS could hold NaN; 0*pad must be 0)
  for (int t = l; t < NK; t += 64) {
    zs[t * 24 + 10] = 0.f;
    zs[t * 24 + 11] = 0.f;
    zs[t * 24 + 22] = 0.f;
    zs[t * 24 + 23] = 0.f;
  }

  const float* __restrict__ Wih = dir ? Wih_b : Wih_f;
  const float* __restrict__ bih = dir ? bih_b : bih_f;
  const float* __restrict__ Whh = dir ? Whh_b : Whh_f;
  const float* __restrict__ bhh = dir ? bhh_b : bhh_f;

  float ur[12], uz[12], un[12];
#pragma unroll
  for (int i = 0; i < 12; ++i) {
    const bool pad = (i >= 10);
    ur[i] = pad ? 0.f : Wih[j * NL + half * 10 + i];
    uz[i] = pad ? 0.f : Wih[(j + 32) * NL + half * 10 + i];
    un[i] = pad ? 0.f : Wih[(j + 64) * NL + half * 10 + i];
  }
  float wr[16], wz[16], wn[16];
#pragma unroll
  for (int i = 0; i < 16; ++i) {
    wr[i] = Whh[j * 32 + hbase + i];
    wz[i] = Whh[(j + 32) * 32 + hbase + i];
    wn[i] = Whh[(j + 64) * 32 + hbase + i];
  }
  const float Br = bih[j] + bhh[j];
  const float Bz = bih[j + 32] + bhh[j + 32];
  const float bin_ = bih[j + 64], bhn = bhh[j + 64];
  float h = 0.f;
  __syncthreads();  // zs visible

  float pir, piz, pin;
  auto inpart = [&](int s, float& xr, float& xz, float& xn) {
    const int tt = dir ? (NK - 1 - s) : s;
    const float* zr = &zs[tt * 24 + half * 12];
    const float4 za = *(const float4*)(zr);
    const float4 zb4 = *(const float4*)(zr + 4);
    const float4 zc = *(const float4*)(zr + 8);
    float ar, az, an;
    ar  = ur[0] * za.x + ur[1] * za.y + ur[2] * za.z + ur[3] * za.w;
    ar += ur[4] * zb4.x + ur[5] * zb4.y + ur[6] * zb4.z + ur[7] * zb4.w;
    ar += ur[8] * zc.x + ur[9] * zc.y + ur[10] * zc.z + ur[11] * zc.w;
    az  = uz[0] * za.x + uz[1] * za.y + uz[2] * za.z + uz[3] * za.w;
    az += uz[4] * zb4.x + uz[5] * zb4.y + uz[6] * zb4.z + uz[7] * zb4.w;
    az += uz[8] * zc.x + uz[9] * zc.y + uz[10] * zc.z + uz[11] * zc.w;
    an  = un[0] * za.x + un[1] * za.y + un[2] * za.z + un[3] * za.w;
    an += un[4] * zb4.x + un[5] * zb4.y + un[6] * zb4.z + un[7] * zb4.w;
    an += un[8] * zc.x + un[9] * zc.y + un[10] * zc.z + un[11] * zc.w;
    xr = ar; xz = az; xn = an;
  };
  inpart(0, pir, piz, pin);

  for (int s = 0; s < NK; ++s) {
    hbuf[j] = h;  // both halves write same value; same-wave in-order
    const float4 h0 = *(const float4*)&hbuf[hbase + 0];
    const float4 h1 = *(const float4*)&hbuf[hbase + 4];
    const float4 h2 = *(const float4*)&hbuf[hbase + 8];
    const float4 h3 = *(const float4*)&hbuf[hbase + 12];
    float ar, az, an;
    ar  = wr[0] * h0.x + wr[1] * h0.y + wr[2] * h0.z + wr[3] * h0.w;
    ar += wr[4] * h1.x + wr[5] * h1.y + wr[6] * h1.z + wr[7] * h1.w;
    ar += wr[8] * h2.x + wr[9] * h2.y + wr[10] * h2.z + wr[11] * h2.w;
    ar += wr[12] * h3.x + wr[13] * h3.y + wr[14] * h3.z + wr[15] * h3.w;
    az  = wz[0] * h0.x + wz[1] * h0.y + wz[2] * h0.z + wz[3] * h0.w;
    az += wz[4] * h1.x + wz[5] * h1.y + wz[6] * h1.z + wz[7] * h1.w;
    az += wz[8] * h2.x + wz[9] * h2.y + wz[10] * h2.z + wz[11] * h2.w;
    az += wz[12] * h3.x + wz[13] * h3.y + wz[14] * h3.z + wz[15] * h3.w;
    an  = wn[0] * h0.x + wn[1] * h0.y + wn[2] * h0.z + wn[3] * h0.w;
    an += wn[4] * h1.x + wn[5] * h1.y + wn[6] * h1.z + wn[7] * h1.w;
    an += wn[8] * h2.x + wn[9] * h2.y + wn[10] * h2.z + wn[11] * h2.w;
    an += wn[12] * h3.x + wn[13] * h3.y + wn[14] * h3.z + wn[15] * h3.w;
    const float cr = pir + ar;
    const float cz = piz + az;
    const float cni = pin;
    const float sr = cr + __shfl_xor(cr, 32);
    const float sz = cz + __shfl_xor(cz, 32);
    const float sni = cni + __shfl_xor(cni, 32);
    const float snh = an + __shfl_xor(an, 32);
    if (s + 1 < NK) inpart(s + 1, pir, piz, pin);  // fills stall slack
    const float rg = fsigmoid(sr + Br);
    const float ug = fsigmoid(sz + Bz);
    const float ng = ftanh(sni + bin_ + rg * (snh + bhn));
    h = ng + ug * (h - ng);
    if (half == 0) {
      const int tt = dir ? (NK - 1 - s) : s;
      val[((size_t)b * NK + tt) * 64 + dir * 32 + j] = h;
    }
  }
}

// R=4 register-reuse attention. Wave = 8 groups x 8 lanes; group owns 4
// q-rows; lane = (group g, d-eighth d8) scores row (lane&3) (2x redundant),
// shares 4 p's via bpermute, accumulates acc[4][8]. k-stagger
// (k = ((g+kb)&7)*64+i) makes every v-load instruction 100% distinct bytes;
// skewed kt LDS (k*16+(k>>6)*4) keeps the 8 groups on disjoint bank quads.
__global__ __launch_bounds__(256, 2) void attn_core_kernel(
    const float* __restrict__ tsteps, const float* __restrict__ ktab,
    const float* __restrict__ val,
    const float* __restrict__ Wq, const float* __restrict__ bq,
    float* __restrict__ att) {
  __shared__ __align__(16) float kts[NK * NE + 32];  // skewed, 33 KB
  __shared__ float wqs[NE * NE];
  __shared__ float bqs[NE];
  const int tid = threadIdx.x;
  for (int i = tid; i < NK * NE; i += 256) {
    const int k = i >> 4, e = i & 15;
    kts[(k << 4) + ((k >> 6) << 2) + e] = ktab[i];
  }
  for (int i = tid; i < NE * NE; i += 256) wqs[i] = Wq[i];
  if (tid < NE) bqs[tid] = bq[tid];
  __syncthreads();

  const int lane = tid & 63;
  const int g = lane >> 3;      // group 0..7
  const int d8 = lane & 7;      // d-eighth
  const int rsel = lane & 3;    // which of the group's 4 rows this lane scores
  const int wave = tid >> 6;
  const int rowbase = blockIdx.x * 128 + wave * 32 + g * 4;
  const int myrow = rowbase + rsel;
  const int b = myrow >> 11;    // uniform per wave (32-row span)

  const float pos = tsteps[myrow];
  const float divs[8] = {1.0f, 0.74989421f, 0.56234133f, 0.42169650f,
                         0.31622777f, 0.23713737f, 0.17782794f, 0.13335214f};
  float emb[NE];
#pragma unroll
  for (int m = 0; m < 8; ++m) {
    float a = 48.0f * pos * divs[m];
    emb[2 * m] = sinf(a);
    emb[2 * m + 1] = cosf(a);
  }
  float q[NE];
#pragma unroll
  for (int e = 0; e < NE; ++e) {
    float acc = bqs[e];
#pragma unroll
    for (int i = 0; i < NE; ++i) acc += emb[i] * wqs[e * NE + i];
    q[e] = acc * 0.25f;  // fold 1/sqrt(E)
  }
  const int lb = lane & ~7;  // group's lane 0 (bpermute sources lb..lb+3)
  const float* __restrict__ vb = val + (size_t)b * NK * 64 + d8 * 8;

  float a0[8], a1[8], a2[8], a3[8];
#pragma unroll
  for (int d = 0; d < 8; ++d) { a0[d] = 0.f; a1[d] = 0.f; a2[d] = 0.f; a3[d] = 0.f; }
  float lsum = 0.f;

  for (int kb = 0; kb < 8; ++kb) {
    const int khi = (g + kb) & 7;                       // k>>6 for this group
    const float* __restrict__ kbase = &kts[(khi << 10) + (khi << 2)];
    const float* __restrict__ vkb = vb + (size_t)(khi << 6) * 64;
#pragma unroll 4
    for (int i = 0; i < 64; ++i) {
      const float4* kr = (const float4*)(kbase + i * 16);
      const float4 k0 = kr[0], k1 = kr[1], k2 = kr[2], k3 = kr[3];
      float s;
      s  = q[0] * k0.x + q[1] * k0.y + q[2] * k0.z + q[3] * k0.w;
      s += q[4] * k1.x + q[5] * k1.y + q[6] * k1.z + q[7] * k1.w;
      s += q[8] * k2.x + q[9] * k2.y + q[10] * k2.z + q[11] * k2.w;
      s += q[12] * k3.x + q[13] * k3.y + q[14] * k3.z + q[15] * k3.w;
      const float p = __expf(s);  // scores O(1): no max-sub needed
      lsum += p;
      const float p0 = bperm(lb + 0, p);
      const float p1 = bperm(lb + 1, p);
      const float p2 = bperm(lb + 2, p);
      const float p3 = bperm(lb + 3, p);
      const float* vr = vkb + i * 64;
      const float4 va = *(const float4*)(vr);
      const float4 vbb = *(const float4*)(vr + 4);
      a0[0] += p0 * va.x; a0[1] += p0 * va.y; a0[2] += p0 * va.z; a0[3] += p0 * va.w;
      a0[4] += p0 * vbb.x; a0[5] += p0 * vbb.y; a0[6] += p0 * vbb.z; a0[7] += p0 * vbb.w;
      a1[0] += p1 * va.x; a1[1] += p1 * va.y; a1[2] += p1 * va.z; a1[3] += p1 * va.w;
      a1[4] += p1 * vbb.x; a1[5] += p1 * vbb.y; a1[6] += p1 * vbb.z; a1[7] += p1 * vbb.w;
      a2[0] += p2 * va.x; a2[1] += p2 * va.y; a2[2] += p2 * va.z; a2[3] += p2 * va.w;
      a2[4] += p2 * vbb.x; a2[5] += p2 * vbb.y; a2[6] += p2 * vbb.z; a2[7] += p2 * vbb.w;
      a3[0] += p3 * va.x; a3[1] += p3 * va.y; a3[2] += p3 * va.z; a3[3] += p3 * va.w;
      a3[4] += p3 * vbb.x; a3[5] += p3 * vbb.y; a3[6] += p3 * vbb.z; a3[7] += p3 * vbb.w;
    }
  }
  // per-row lsums (complete: each lane's own row covered all 512 k)
  const float l0 = bperm(lb + 0, lsum);
  const float l1 = bperm(lb + 1, lsum);
  const float l2 = bperm(lb + 2, lsum);
  const float l3 = bperm(lb + 3, lsum);
  const float i0 = 1.0f / l0, i1 = 1.0f / l1, i2 = 1.0f / l2, i3 = 1.0f / l3;
  float* ob = att + (size_t)rowbase * 64 + d8 * 8;
#pragma unroll
  for (int d4 = 0; d4 < 2; ++d4) {
    float4 o;
    o.x = a0[d4 * 4 + 0] * i0; o.y = a0[d4 * 4 + 1] * i0;
    o.z = a0[d4 * 4 + 2] * i0; o.w = a0[d4 * 4 + 3] * i0;
    *(float4*)(ob + 0 * 64 + d4 * 4) = o;
    o.x = a1[d4 * 4 + 0] * i1; o.y = a1[d4 * 4 + 1] * i1;
    o.z = a1[d4 * 4 + 2] * i1; o.w = a1[d4 * 4 + 3] * i1;
    *(float4*)(ob + 1 * 64 + d4 * 4) = o;
    o.x = a2[d4 * 4 + 0] * i2; o.y = a2[d4 * 4 + 1] * i2;
    o.z = a2[d4 * 4 + 2] * i2; o.w = a2[d4 * 4 + 3] * i2;
    *(float4*)(ob + 2 * 64 + d4 * 4) = o;
    o.x = a3[d4 * 4 + 0] * i3; o.y = a3[d4 * 4 + 1] * i3;
    o.z = a3[d4 * 4 + 2] * i3; o.w = a3[d4 * 4 + 3] * i3;
    *(float4*)(ob + 3 * 64 + d4 * 4) = o;
  }
}

// Per-row MLP on folded weights: out = W2 @ relu(W1' @ ar + b1') + b2.
__global__ __launch_bounds__(256) void mlp_kernel(
    const float* __restrict__ att,
    const float* __restrict__ w1p, const float* __restrict__ b1p,
    const float* __restrict__ W2, const float* __restrict__ b2,
    float* __restrict__ out) {
  __shared__ __align__(16) float w1s[NHID * 64];   // 12.8 KB
  __shared__ __align__(16) float w2s[NO * NHID];   // 8.2 KB
  __shared__ float b1s[NHID], b2s[NO];
  const int tid = threadIdx.x;
  for (int i = tid; i < NHID * 64; i += 256) w1s[i] = w1p[i];
  for (int i = tid; i < NO * NHID; i += 256) w2s[i] = W2[i];
  if (tid < NHID) b1s[tid] = b1p[tid];
  if (tid < NO) b2s[tid] = b2[tid];
  __syncthreads();

  const int row = blockIdx.x * 256 + tid;
  float ar[64];
  const float4* a4 = (const float4*)(att + (size_t)row * 64);
#pragma unroll
  for (int d4 = 0; d4 < 16; ++d4) {
    float4 v = a4[d4];
    ar[d4 * 4 + 0] = v.x;
    ar[d4 * 4 + 1] = v.y;
    ar[d4 * 4 + 2] = v.z;
    ar[d4 * 4 + 3] = v.w;
  }
  float outv[NO];
#pragma unroll
  for (int oo = 0; oo < NO; ++oo) outv[oo] = b2s[oo];
#pragma unroll 2
  for (int o = 0; o < NHID; ++o) {
    float acc = b1s[o];
    const float4* w4 = (const float4*)&w1s[o * 64];
#pragma unroll
    for (int i4 = 0; i4 < 16; ++i4) {
      float4 ww = w4[i4];
      acc += ar[i4 * 4 + 0] * ww.x + ar[i4 * 4 + 1] * ww.y +
             ar[i4 * 4 + 2] * ww.z + ar[i4 * 4 + 3] * ww.w;
    }
    const float hv = fmaxf(acc, 0.f);
#pragma unroll
    for (int oo = 0; oo < NO; ++oo) outv[oo] += hv * w2s[oo * NHID + o];
  }
  float* orow = out + (size_t)row * NO;
#pragma unroll
  for (int oo = 0; oo < NO; ++oo) orow[oo] = outv[oo];
}

extern "C" void kernel_launch(void* const* d_in, const int* in_sizes, int n_in,
                              void* d_out, int out_size, void* d_ws, size_t ws_size,
                              hipStream_t stream) {
  const float* z = (const float*)d_in[0];
  const float* ts = (const float*)d_in[1];
  const float* refq = (const float*)d_in[2];
  const float* Wih_f = (const float*)d_in[3];
  const float* Whh_f = (const float*)d_in[4];
  const float* bih_f = (const float*)d_in[5];
  const float* bhh_f = (const float*)d_in[6];
  const float* Wih_b = (const float*)d_in[7];
  const float* Whh_b = (const float*)d_in[8];
  const float* bih_b = (const float*)d_in[9];
  const float* bhh_b = (const float*)d_in[10];
  const float* Wq = (const float*)d_in[11];
  const float* bq = (const float*)d_in[12];
  const float* Wk = (const float*)d_in[13];
  const float* bk = (const float*)d_in[14];
  const float* Wv = (const float*)d_in[15];
  const float* bv = (const float*)d_in[16];
  const float* W1 = (const float*)d_in[17];
  const float* b1 = (const float*)d_in[18];
  const float* W2 = (const float*)d_in[19];
  const float* b2 = (const float*)d_in[20];

  float* ws = (float*)d_ws;
  float* att = ws;              // 4,194,304
  float* val = ws + 4194304;    // 1,048,576
  float* ktab = ws + 5242880;   // 8,192
  float* w1p = ws + 5251072;    // 3,200
  float* b1p = ws + 5254272;    // 64
  float* out = (float*)d_out;

  prep_kernel<<<3, 256, 0, stream>>>(refq, Wk, bk, Wv, bv, W1, b1,
                                     ktab, w1p, b1p);
  gru_kernel<<<64, 64, 0, stream>>>(z, Wih_f, bih_f, Whh_f, bhh_f,
                                    Wih_b, bih_b, Whh_b, bhh_b, val);
  attn_core_kernel<<<512, 256, 0, stream>>>(ts, ktab, val, Wq, bq, att);
  mlp_kernel<<<256, 256, 0, stream>>>(att, w1p, b1p, W2, b2, out);
}